// Round 8
// baseline (70.783 us; speedup 1.0000x reference)
//
#include <hip/hip_runtime.h>

#define N_NODES 40000
#define C_DIM   128
#define K_NBR   16

static constexpr float BETA_F  = 0.11778303565638346f;  // log(1.125)
static constexpr float C1_F    = 0.7939952679092549f;   // (1-ALPHA)*(1-BETA)
static constexpr float C2_F    = 0.08822169643436166f;  // ALPHA*(1-BETA)
static constexpr float SCALE_X  = BETA_F / 17.0f;       // applied to x
static constexpr float SCALE_X0 = BETA_F;               // applied to x0
static constexpr float CD1_F = C1_F / BETA_F;           // diag coeff on scaled x
static constexpr float CD2_F = C2_F / BETA_F;           // diag coeff on scaled x0

typedef __attribute__((ext_vector_type(8))) short bf16x8;
typedef __attribute__((ext_vector_type(4))) float f32x4;

__device__ __forceinline__ unsigned pack_bf16x2(float a, float b) {
    unsigned ua = __float_as_uint(a), ub = __float_as_uint(b);
    ua += 0x7fffu + ((ua >> 16) & 1u);     // RNE
    ub += 0x7fffu + ((ub >> 16) & 1u);
    return (ua >> 16) | (ub & 0xffff0000u);
}
__device__ __forceinline__ float bflo(unsigned u) { return __uint_as_float(u << 16); }
__device__ __forceinline__ float bfhi(unsigned u) { return __uint_as_float(u & 0xffff0000u); }

// Build a B-fragment (bf16x8) from 8 consecutive f32 weights.
__device__ __forceinline__ bf16x8 pack_w8(const float* wp) {
    const float4 wa = *(const float4*)wp;
    const float4 wb = *(const float4*)(wp + 4);
    unsigned u[4];
    u[0] = pack_bf16x2(wa.x, wa.y);
    u[1] = pack_bf16x2(wa.z, wa.w);
    u[2] = pack_bf16x2(wb.x, wb.y);
    u[3] = pack_bf16x2(wb.z, wb.w);
    uint4 uu = make_uint4(u[0], u[1], u[2], u[3]);
    return *(bf16x8*)&uu;
}

// ---------------------------------------------------------------------------
// Kernel G: z1T[j][o] = (BETA/17)*sum_c x[c][j]*W1[o][c] + (C1/17)*x[o][j]
// Grid 1250 x 256 thr; 32 nodes/block. x read coalesced along n, transposed
// through LDS (scaled by BETA/17, bf16). W1 fragments loaded from global
// (L2-hit) with the same slot map as A (symmetric A/B k-mapping).
// ---------------------------------------------------------------------------
__global__ __launch_bounds__(256) void z1_kernel(
        const float* __restrict__ x,      // [128][40000]
        const float* __restrict__ W1,     // [128][128]
        unsigned* __restrict__ z1T) {     // [N][64] u32 = bf16x2
    __shared__ unsigned xs[32 * 68];      // [n][c2] scaled x^T, stride 68 u32

    const int nb  = blockIdx.x * 32;
    const int tid = threadIdx.x;

    // ---- stage: transpose+cast+scale 32n x 128c (R7-proven pattern) ----
    {
        const int c2 = tid >> 2;          // 0..63
        const int h  = tid & 3;           // n-offset h*8
        const float* r0 = &x[(size_t)(2 * c2)     * N_NODES + nb + h * 8];
        const float* r1 = &x[(size_t)(2 * c2 + 1) * N_NODES + nb + h * 8];
        const float4 a0 = *(const float4*)(r0);
        const float4 a1 = *(const float4*)(r0 + 4);
        const float4 b0 = *(const float4*)(r1);
        const float4 b1 = *(const float4*)(r1 + 4);
        unsigned* lr = &xs[(h * 8) * 68 + c2];
        lr[0 * 68] = pack_bf16x2(a0.x * SCALE_X, b0.x * SCALE_X);
        lr[1 * 68] = pack_bf16x2(a0.y * SCALE_X, b0.y * SCALE_X);
        lr[2 * 68] = pack_bf16x2(a0.z * SCALE_X, b0.z * SCALE_X);
        lr[3 * 68] = pack_bf16x2(a0.w * SCALE_X, b0.w * SCALE_X);
        lr[4 * 68] = pack_bf16x2(a1.x * SCALE_X, b1.x * SCALE_X);
        lr[5 * 68] = pack_bf16x2(a1.y * SCALE_X, b1.y * SCALE_X);
        lr[6 * 68] = pack_bf16x2(a1.z * SCALE_X, b1.z * SCALE_X);
        lr[7 * 68] = pack_bf16x2(a1.w * SCALE_X, b1.w * SCALE_X);
    }
    __syncthreads();

    const int lane = tid & 63;
    const int wid  = tid >> 6;
    const int nh = wid & 1, oh = wid >> 1;
    const int arow = nh * 16 + (lane & 15);
    const int acol = (lane >> 4) * 4;

    bf16x8 af[4];
#pragma unroll
    for (int kb = 0; kb < 4; ++kb)
        af[kb] = *(const bf16x8*)&xs[arow * 68 + kb * 16 + acol];

    const int ob = oh * 64 + (lane & 15);
    const int cb = (lane >> 4) * 8;
    const int rbase = nh * 16 + (lane >> 4) * 4;
    const bool hi = (lane & 1) != 0;

#pragma unroll
    for (int t = 0; t < 4; ++t) {
        const int o = ob + t * 16;
        f32x4 a = {0.f, 0.f, 0.f, 0.f};
#pragma unroll
        for (int kb = 0; kb < 4; ++kb) {
            const bf16x8 bw = pack_w8(&W1[(size_t)o * C_DIM + kb * 32 + cb]);
            a = __builtin_amdgcn_mfma_f32_16x16x32_bf16(af[kb], bw, a, 0, 0, 0);
        }
        // diag term + shfl-pack to bf16 pairs, even lanes store u32
#pragma unroll
        for (int r = 0; r < 4; ++r) {
            const int row = rbase + r;
            const unsigned ux = xs[row * 68 + (o >> 1)];
            float v = a[r] + CD1_F * (hi ? bfhi(ux) : bflo(ux));
            const float vp = __shfl_xor(v, 1);
            if (!hi) {
                z1T[(size_t)(nb + row) * 64 + (o >> 1)] = pack_bf16x2(v, vp);
            }
        }
    }
}

// ---------------------------------------------------------------------------
// Kernel S: out[o][n] = relu( sum_{j in N+(n)} z1T[j][o]
//                             + BETA*sum_c x0[n][c]W2[o][c] + C2*x0[n][o]
//                             + bias[o] )
// Grid 1250 x 256 thr; 32 nodes/block. z2 computed block-locally (MFMA on
// staged x0); gather is pure bf16-row sums; transpose-write via LDS with
// full 128-B out lines.
// ---------------------------------------------------------------------------
__global__ __launch_bounds__(256) void gather_kernel(
        const unsigned* __restrict__ z1T,   // [N][64] u32 = bf16x2
        const float*    __restrict__ x0,    // [N][128]
        const float*    __restrict__ W2,    // [128][128]
        const float*    __restrict__ bias,  // [128]
        const int*      __restrict__ e0,    // [N][16]
        float*          __restrict__ out) { // [128][N]
    __shared__ int      eis[512];
    __shared__ unsigned x0s[32 * 68];       // scaled x0, bf16x2, stride 68
    __shared__ float    zbuf[32 * 132];     // [n][o] f32, stride 132

    const int nb  = blockIdx.x * 32;
    const int tid = threadIdx.x;
    const int lane = tid & 63;
    const int wid  = tid >> 6;

    eis[tid]       = e0[(size_t)nb * K_NBR + tid];
    eis[256 + tid] = e0[(size_t)nb * K_NBR + 256 + tid];

    // ---- stage x0 tile (scaled by BETA) ----
    {
        const int n = tid >> 3, g = tid & 7;
        const float* r = &x0[(size_t)(nb + n) * C_DIM + g * 16];
        const float4 v0 = *(const float4*)(r);
        const float4 v1 = *(const float4*)(r + 4);
        const float4 v2 = *(const float4*)(r + 8);
        const float4 v3 = *(const float4*)(r + 12);
        uint4 ua, ub;
        ua.x = pack_bf16x2(v0.x * SCALE_X0, v0.y * SCALE_X0);
        ua.y = pack_bf16x2(v0.z * SCALE_X0, v0.w * SCALE_X0);
        ua.z = pack_bf16x2(v1.x * SCALE_X0, v1.y * SCALE_X0);
        ua.w = pack_bf16x2(v1.z * SCALE_X0, v1.w * SCALE_X0);
        ub.x = pack_bf16x2(v2.x * SCALE_X0, v2.y * SCALE_X0);
        ub.y = pack_bf16x2(v2.z * SCALE_X0, v2.w * SCALE_X0);
        ub.z = pack_bf16x2(v3.x * SCALE_X0, v3.y * SCALE_X0);
        ub.w = pack_bf16x2(v3.z * SCALE_X0, v3.w * SCALE_X0);
        *(uint4*)&x0s[n * 68 + g * 8]     = ua;
        *(uint4*)&x0s[n * 68 + g * 8 + 4] = ub;
    }
    __syncthreads();

    // ---- z2 GEMM (result held in regs through the gather phase) ----
    const int nh = wid & 1, oh = wid >> 1;
    const int arow = nh * 16 + (lane & 15);
    const int acol = (lane >> 4) * 4;
    bf16x8 af[4];
#pragma unroll
    for (int kb = 0; kb < 4; ++kb)
        af[kb] = *(const bf16x8*)&x0s[arow * 68 + kb * 16 + acol];

    const int ob = oh * 64 + (lane & 15);
    const int cb = (lane >> 4) * 8;
    f32x4 acc[4];
#pragma unroll
    for (int t = 0; t < 4; ++t) {
        f32x4 a = {0.f, 0.f, 0.f, 0.f};
#pragma unroll
        for (int kb = 0; kb < 4; ++kb) {
            const bf16x8 bw = pack_w8(&W2[(size_t)(ob + t * 16) * C_DIM + kb * 32 + cb]);
            a = __builtin_amdgcn_mfma_f32_16x16x32_bf16(af[kb], bw, a, 0, 0, 0);
        }
        acc[t] = a;
    }

    // ---- gather: half-wave per node, pure bf16-row sums ----
    const int hw = tid >> 5, l5 = tid & 31;
#pragma unroll 1
    for (int p = 0; p < 4; ++p) {
        const int local = hw * 4 + p;
        const int n = nb + local;
        const uint2 sv = *(const uint2*)&z1T[(size_t)n * 64 + 2 * l5];  // self
        float s0 = bflo(sv.x), s1 = bfhi(sv.x);
        float s2 = bflo(sv.y), s3 = bfhi(sv.y);
        const int* ep = &eis[local * K_NBR];
#pragma unroll
        for (int k = 0; k < K_NBR; ++k) {
            const int j = ep[k];
            const uint2 v = *(const uint2*)&z1T[(size_t)j * 64 + 2 * l5];
            s0 += bflo(v.x); s1 += bfhi(v.x);
            s2 += bflo(v.y); s3 += bfhi(v.y);
        }
        *(f32x4*)&zbuf[local * 132 + 4 * l5] = (f32x4){s0, s1, s2, s3};
    }
    __syncthreads();

    // ---- epilogue: zbuf += z2 + diag + bias; relu ----
    const int rbase = nh * 16 + (lane >> 4) * 4;
    const bool hi = (lane & 1) != 0;
#pragma unroll
    for (int t = 0; t < 4; ++t) {
        const int o = ob + t * 16;
        const float bo = bias[o];
#pragma unroll
        for (int r = 0; r < 4; ++r) {
            const int row = rbase + r;
            const unsigned ux = x0s[row * 68 + (o >> 1)];
            const float x0v = hi ? bfhi(ux) : bflo(ux);
            float v = zbuf[row * 132 + o] + acc[t][r] + CD2_F * x0v + bo;
            zbuf[row * 132 + o] = v > 0.0f ? v : 0.0f;
        }
    }
    __syncthreads();

    // ---- transpose-write: full 128-B out lines ----
    const int o  = tid >> 1;
    const int hh = tid & 1;
    float* op = &out[(size_t)o * N_NODES + nb + hh * 16];
#pragma unroll
    for (int m = 0; m < 4; ++m) {
        const int i = 4 * m;
        float4 v;
        v.x = zbuf[(hh * 16 + i + 0) * 132 + o];
        v.y = zbuf[(hh * 16 + i + 1) * 132 + o];
        v.z = zbuf[(hh * 16 + i + 2) * 132 + o];
        v.w = zbuf[(hh * 16 + i + 3) * 132 + o];
        *(float4*)(op + i) = v;
    }
}

// ---------------------------------------------------------------------------
extern "C" void kernel_launch(void* const* d_in, const int* in_sizes, int n_in,
                              void* d_out, int out_size, void* d_ws, size_t ws_size,
                              hipStream_t stream) {
    const float* x    = (const float*)d_in[0];   // [1,128,40000,1]
    const float* x0   = (const float*)d_in[1];   // [1,40000,128]
    const int*   ei   = (const int*)  d_in[2];   // [2,1,40000,16]; row 0
    const float* W1   = (const float*)d_in[3];   // [128,128]
    const float* W2   = (const float*)d_in[4];   // [128,128]
    const float* bias = (const float*)d_in[5];   // [128]
    float* out = (float*)d_out;                  // [1,128,40000,1]

    unsigned* z1T = (unsigned*)d_ws;             // 40000*64 u32 = 10.24 MB

    hipLaunchKernelGGL(z1_kernel, dim3(1250), dim3(256), 0, stream,
                       x, W1, z1T);
    hipLaunchKernelGGL(gather_kernel, dim3(1250), dim3(256), 0, stream,
                       z1T, x0, W2, bias, ei, out);
}